// Round 14
// baseline (4751.475 us; speedup 1.0000x reference)
//
#include <hip/hip_runtime.h>
#include <math.h>

#define DICT 1024
#define IN_DIM 512
#define BATCH 256
#define LMBD_F 0.1f
#define TOL2 1e-8f       // tol^2 (compare squared row norms)
#define MAX_ITERS 1000
#define LM 64            // Lanczos iterations

// ---- workspace layout (float offsets) ----
#define OFF_G      0u            // 1024*1024 f32 Gram
#define OFF_B      1048576u      // 256*1024 f32  b = x D^T
#define OFF_HA     1310720u      // (unused now; h lives in registers)
#define OFF_W      1572864u      // 1024 Lanczos w (only shared Lanczos state)
#define OFF_RDP    1573888u      // 4096: per-block row-delta partials [bid*16 + r]
#define OFF_FLG    1577984u      // 4096 uints: 256 flags, stride 16 (64B lines)
#define OFF_PM     1582080u      // podmask (uint) + pad
#define OFF_BF     1582592u      // bf16 h arrays: 4 x 262144 ushort (hiA,loA,hiB,loB)
#define OFF_GBF    2106880u      // bf16 G arrays: 2 x 1048576 ushort (Ghi,Glo)

typedef __attribute__((ext_vector_type(8))) short short8v;  // 8 bf16
typedef __attribute__((ext_vector_type(4))) float f32x4;    // MFMA C/D + asm operands
typedef __attribute__((ext_vector_type(4))) int i32x4;      // asm 16B payload

#define MFMA16(a, b, c) __builtin_amdgcn_mfma_f32_16x16x32_bf16(a, b, c, 0, 0, 0)

__device__ __forceinline__ ushort f2bf(float v) {      // f32 -> bf16 (RNE)
    union { float f; unsigned u; } x; x.f = v;
    unsigned r = x.u + 0x7fffu + ((x.u >> 16) & 1u);
    return (ushort)(r >> 16);
}
__device__ __forceinline__ float bf2f(ushort b) {
    union { unsigned u; float f; } x; x.u = ((unsigned)b) << 16;
    return x.f;
}
__device__ __forceinline__ float softthr(float aa, float th) {
    float s = fabsf(aa) - th;
    return s > 0.f ? copysignf(s, aa) : 0.f;
}

// ---- device-coherent access: sc1 = bypass L1/L2, served at IC ----
__device__ __forceinline__ void vmdrain() { asm volatile("s_waitcnt vmcnt(0)" ::: "memory"); }
__device__ __forceinline__ unsigned ld_flag(const unsigned* p) {
    unsigned v;
    asm volatile("global_load_dword %0, %1, off sc1\ns_waitcnt vmcnt(0)" : "=v"(v) : "v"(p) : "memory");
    return v;
}
// fire-and-forget flag store: ordering established by vmdrain() BEFORE it
__device__ __forceinline__ void st_flag(unsigned* p, unsigned v) {
    asm volatile("global_store_dword %0, %1, off sc1" :: "v"(p), "v"(v) : "memory");
}
__device__ __forceinline__ float ld_f_sc(const float* p) {
    float v;
    asm volatile("global_load_dword %0, %1, off sc1\ns_waitcnt vmcnt(0)" : "=v"(v) : "v"(p) : "memory");
    return v;
}
__device__ __forceinline__ void st_f_sc(float* p, float v) {
    asm volatile("global_store_dword %0, %1, off sc1" :: "v"(p), "v"(v) : "memory");
}
__device__ __forceinline__ f32x4 ld_f4_sc(const float* p) {
    f32x4 v;
    asm volatile("global_load_dwordx4 %0, %1, off sc1\ns_waitcnt vmcnt(0)" : "=v"(v) : "v"(p) : "memory");
    return v;
}
__device__ __forceinline__ void st_u_sc(unsigned* p, unsigned v) {
    asm volatile("global_store_dword %0, %1, off sc1" :: "v"(p), "v"(v) : "memory");
}
// no-wait loads: caller MUST vmdrain + sched_barrier(0) before using results (rule #18)
__device__ __forceinline__ void ld_a16(i32x4* d, const void* p) {
    asm volatile("global_load_dwordx4 %0, %1, off sc1" : "=v"(*d) : "v"(p));
}
__device__ __forceinline__ void ld_u_nw(unsigned* d, const unsigned* p) {
    asm volatile("global_load_dword %0, %1, off sc1" : "=v"(*d) : "v"(p));
}
__device__ __forceinline__ void ld_f_nw(float* d, const float* p) {
    asm volatile("global_load_dword %0, %1, off sc1" : "=v"(*d) : "v"(p));
}

// ---------------- init (runs every launch: resets ALL iteration state) ----------------
__global__ void k_init(float* ws) {
    int t = threadIdx.x;  // 1024 threads
    unsigned* flg = (unsigned*)(ws + OFF_FLG);
#pragma unroll
    for (int j = 0; j < 4; ++j) flg[t + 1024 * j] = 0u;
#pragma unroll
    for (int j = 0; j < 4; ++j) ws[OFF_RDP + t + 1024 * j] = 1e30f;
    if (t == 0) *(unsigned*)(ws + OFF_PM) = 0u;
}

// ---------------- one-time NT GEMM: C[M,N] = A[M,K] * B[N,K]^T ----------------
__global__ void k_gemm_nt(float* __restrict__ C, const float* __restrict__ A,
                          const float* __restrict__ B, int M, int N, int K) {
    __shared__ float As[32][33];
    __shared__ float Bs[32][33];
    const int tid = threadIdx.x;
    const int m0 = blockIdx.y * 32, n0 = blockIdx.x * 32;
    const int lrw = tid >> 3;
    const int lc4 = (tid & 7) * 4;
    const int ty = tid >> 4, tx = tid & 15;
    float acc00 = 0, acc01 = 0, acc10 = 0, acc11 = 0;
    for (int k0 = 0; k0 < K; k0 += 32) {
        float4 av = *(const float4*)&A[(m0 + lrw) * K + k0 + lc4];
        float4 bv = *(const float4*)&B[(n0 + lrw) * K + k0 + lc4];
        __syncthreads();
        As[lrw][lc4 + 0] = av.x; As[lrw][lc4 + 1] = av.y;
        As[lrw][lc4 + 2] = av.z; As[lrw][lc4 + 3] = av.w;
        Bs[lrw][lc4 + 0] = bv.x; Bs[lrw][lc4 + 1] = bv.y;
        Bs[lrw][lc4 + 2] = bv.z; Bs[lrw][lc4 + 3] = bv.w;
        __syncthreads();
#pragma unroll
        for (int k = 0; k < 32; ++k) {
            float a0 = As[ty * 2][k], a1 = As[ty * 2 + 1][k];
            float b0 = Bs[tx * 2][k], b1 = Bs[tx * 2 + 1][k];
            acc00 += a0 * b0; acc01 += a0 * b1;
            acc10 += a1 * b0; acc11 += a1 * b1;
        }
    }
    C[(m0 + ty * 2) * N + n0 + tx * 2] = acc00;
    C[(m0 + ty * 2) * N + n0 + tx * 2 + 1] = acc01;
    C[(m0 + ty * 2 + 1) * N + n0 + tx * 2] = acc10;
    C[(m0 + ty * 2 + 1) * N + n0 + tx * 2 + 1] = acc11;
}

// ---------------- convert G f32 -> (Ghi, Glo) bf16, once ----------------
__global__ void k_conv_g(float* ws) {
    const int i = (blockIdx.x * 256 + threadIdx.x) * 4;
    const float* G = ws + OFF_G;
    ushort* Ghi = (ushort*)(ws + OFF_GBF);
    ushort* Glo = Ghi + 1048576u;
    float4 g = *(const float4*)&G[i];
    ushort h0 = f2bf(g.x), h1 = f2bf(g.y), h2 = f2bf(g.z), h3 = f2bf(g.w);
    *(ushort4*)&Ghi[i] = make_ushort4(h0, h1, h2, h3);
    ushort l0 = f2bf(g.x - bf2f(h0)), l1 = f2bf(g.y - bf2f(h1));
    ushort l2 = f2bf(g.z - bf2f(h2)), l3 = f2bf(g.w - bf2f(h3));
    *(ushort4*)&Glo[i] = make_ushort4(l0, l1, l2, l3);
}

// ---------------- persistent kernel ----------------
// 256 blocks x 512 threads. ISTA: per-wave producer dataflow (wave w waits on
// its 2 K-range producers), h/b in registers, pre-issued flag reads fold the
// poll RTT into the previous iteration's tail. Flag word =
// (gen<<2)|(bit_cur<<1)|bit_prev; drift<=1 -> bit-at-gen well-defined ->
// unanimous stop. Bookkeeper cadence 4, off-path.
__launch_bounds__(512, 2)
__global__ void k_persist(float* __restrict__ ws, float* __restrict__ dout) {
    const int tid = threadIdx.x;
    const int bid = blockIdx.x;
    const int w = tid >> 6, lane = tid & 63;
    unsigned* flg = (unsigned*)(ws + OFF_FLG);
    unsigned* podmask = (unsigned*)(ws + OFF_PM);
    float* Wg = ws + OFF_W;
    float* rdp = ws + OFF_RDP;
    const float* G = ws + OFF_G;

    __shared__ float Ps[8][16][64];   // split-K partials, 32 KB
    __shared__ float Vl[1024], VPl[1024], Wl[1024];
    __shared__ float aArr[LM], bArr[LM];
    __shared__ float sred[8];
    __shared__ float scal2[2];
    __shared__ unsigned sres;
    __shared__ unsigned sbits[16];
    __shared__ unsigned sStick;

    unsigned gen = 0;

    const int bx = bid & 15;            // col tile (64 cols)
    const int by = bid >> 4;            // row tile (16 rows) == pod id
    const int R0 = by * 16, C0 = bx * 64;
    const int pod16 = by * 16;          // first bid of pod

    // ================= Lanczos: redundant alpha/beta, shared W only =================
    if (tid < 512) {
        Vl[tid] = 0.03125f; Vl[tid + 512] = 0.03125f;
        VPl[tid] = 0.f;     VPl[tid + 512] = 0.f;
    }
    __syncthreads();
    float bprev = 0.f;
#pragma unroll 1
    for (int j = 0; j < LM; ++j) {
        // matvec: this block computes W rows 4*bid .. 4*bid+3 from local Vl
        {
            const int row = tid >> 7, sub = tid & 127;
            const float* gr = G + (bid * 4 + row) * DICT;
            float s = 0.f;
#pragma unroll
            for (int jj = 0; jj < 8; ++jj) s += gr[sub + 128 * jj] * Vl[sub + 128 * jj];
#pragma unroll
            for (int off = 32; off; off >>= 1) s += __shfl_down(s, off);
            if (lane == 0) sred[w] = s;
            __syncthreads();
            if (tid < 4) st_f_sc(Wg + bid * 4 + tid, sred[2 * tid] + sred[2 * tid + 1]);
        }
        // global parallel flag barrier
        ++gen;
        vmdrain(); __syncthreads();
        if (tid == 0) st_flag(&flg[bid * 16], gen << 2);
        if (w == 0) {
            for (;;) {
                unsigned v0, v1, v2, v3;
                ld_u_nw(&v0, &flg[lane * 16]);
                ld_u_nw(&v1, &flg[(lane + 64) * 16]);
                ld_u_nw(&v2, &flg[(lane + 128) * 16]);
                ld_u_nw(&v3, &flg[(lane + 192) * 16]);
                vmdrain(); __builtin_amdgcn_sched_barrier(0);
                bool ok = ((v0 >> 2) >= gen) && ((v1 >> 2) >= gen) &&
                          ((v2 >> 2) >= gen) && ((v3 >> 2) >= gen);
                if (__ballot(ok) == ~0ull) break;
                __builtin_amdgcn_s_sleep(1);
            }
        }
        __syncthreads();
        // redundant: read full W, compute alpha/beta, update Vl/VPl locally
        if (tid < 256) { f32x4 w4 = ld_f4_sc(Wg + tid * 4); *(f32x4*)&Wl[tid * 4] = w4; }
        __syncthreads();
        float p = Vl[tid] * Wl[tid] + Vl[tid + 512] * Wl[tid + 512];
#pragma unroll
        for (int off = 32; off; off >>= 1) p += __shfl_down(p, off);
        if (lane == 0) sred[w] = p;
        __syncthreads();
        float alpha = sred[0] + sred[1] + sred[2] + sred[3] + sred[4] + sred[5] + sred[6] + sred[7];
        float u0 = Wl[tid] - alpha * Vl[tid] - bprev * VPl[tid];
        float u1 = Wl[tid + 512] - alpha * Vl[tid + 512] - bprev * VPl[tid + 512];
        float qq = u0 * u0 + u1 * u1;
        __syncthreads();   // sred reuse
#pragma unroll
        for (int off = 32; off; off >>= 1) qq += __shfl_down(qq, off);
        if (lane == 0) sred[w] = qq;
        __syncthreads();
        float beta = sqrtf(sred[0] + sred[1] + sred[2] + sred[3] + sred[4] + sred[5] + sred[6] + sred[7]);
        float bsafe = (beta > 1e-20f) ? beta : 0.f;
        float inv = (beta > 1e-20f) ? 1.f / beta : 0.f;
        VPl[tid] = Vl[tid]; VPl[tid + 512] = Vl[tid + 512];
        Vl[tid] = u0 * inv; Vl[tid + 512] = u1 * inv;
        if (tid == 0) { aArr[j] = alpha; bArr[j] = bsafe; }
        bprev = bsafe;
        __syncthreads();
    }

    // ================= Sturm bisection (per block, wave 0) -> lr, thresh =================
    if (tid < 64) {
        double lo = 0.0, hi = 0.0;
        for (int i = 0; i < LM; ++i) {
            double bi  = fabs((double)bArr[i]);
            double bim = i ? fabs((double)bArr[i - 1]) : 0.0;
            double r = (double)aArr[i] + bi + bim;
            if (r > hi) hi = r;
        }
        for (int rnd = 0; rnd < 4; ++rnd) {
            double midt = lo + (hi - lo) * ((double)(tid + 1) / 65.0);
            int cntn = 0; double d = 1.0;
            for (int i = 0; i < LM; ++i) {
                double bm = i ? (double)bArr[i - 1] : 0.0;
                d = ((double)aArr[i] - midt) - (bm * bm) / d;
                if (d == 0.0) d = -1e-300;
                if (d < 0.0) cntn++;
            }
            unsigned long long m = __ballot(cntn >= LM);
            int first = (m == 0ull) ? 64 : (__ffsll((unsigned long long)m) - 1);
            double nlo = lo + (hi - lo) * ((double)first / 65.0);
            double nhi = (first == 64) ? hi : lo + (hi - lo) * ((double)(first + 1) / 65.0);
            lo = nlo; hi = nhi;
        }
        if (tid == 0) {
            float lam = (float)(0.5 * (lo + hi));
            float lrv = 0.99f / lam;
            scal2[0] = lrv;
            scal2[1] = lrv * LMBD_F;
        }
    }
    if (tid == 0) sStick = 0u;
    __syncthreads();
    const float lr = scal2[0], th = scal2[1];

    // ================= ISTA: per-wave producer dataflow, h/b in registers =================
    ushort* bfb = (ushort*)(ws + OFF_BF);
    const ushort* Ghi = (const ushort*)(ws + OFF_GBF);
    const float* bv_ = ws + OFF_B;
    const int r16 = lane & 15, kk8 = (lane >> 4) * 8;
    const int er = tid >> 5;          // 0..15
    const int ec = (tid & 31) * 2;    // 0..62

    // hoist G fragments into registers (reused all iters)
    const ushort* pB = Ghi + (C0 + r16) * DICT + w * 128 + kk8;
    short8v bh[4][4], bl[4][4];
#pragma unroll
    for (int ks = 0; ks < 4; ++ks)
#pragma unroll
        for (int jj = 0; jj < 4; ++jj) {
            bh[ks][jj] = *(const short8v*)(pB + jj * 16 * DICT + ks * 32);
            bl[ks][jj] = *(const short8v*)(pB + 1048576u + jj * 16 * DICT + ks * 32);
        }

    // per-thread persistent state: h values and b values for our 2 outputs
    const int gi0 = (R0 + er) * DICT + C0 + ec;
    const float2 breg = *(const float2*)&bv_[gi0];
    float hc0 = 0.f, hc1 = 0.f;

    unsigned sticky = 0, stPub = 0;
    // this wave's two producer flags (own K-range [w*128, w*128+128))
    const unsigned* fprod0 = &flg[(pod16 + 2 * w) * 16];
    const unsigned* fprod1 = &flg[(pod16 + 2 * w + 1) * 16];
    unsigned vpre = 0;                // pre-issued flag read (lanes 0,1)

#pragma unroll 1
    for (int it = 0; it < MAX_ITERS; ++it) {
        const ushort* hi_in = bfb + ((it & 1) ? 524288u : 0u);
        ushort* hi_out = bfb + ((it & 1) ? 0u : 524288u);

        // ---- producer wait; pre-issued read (prev iter tail) folds poll RTT ----
        if (it > 0) vmdrain();        // completes pre-issued vpre
        if (lane < 2) {
            const unsigned* fp = lane ? fprod1 : fprod0;
            unsigned v = (it > 0) ? vpre : 0u;
            int spins = 0;
            while ((v >> 2) < gen) {
                v = ld_flag(fp);
                if ((v >> 2) >= gen) break;
                __builtin_amdgcn_s_sleep(1);
                if (++spins > (1 << 25)) break;    // diagnostic bail (unreachable if sound)
            }
            // drift <= 1: flag gen == gen -> cur bit; gen+1 -> prev bit
            sbits[2 * w + lane] = ((v >> 2) == gen) ? ((v >> 1) & 1u) : (v & 1u);
        }
        // wave reconverged: producers' h visible; issue A-loads for our K-chunk
        const ushort* pA = hi_in + (R0 + r16) * DICT + w * 128 + kk8;
        i32x4 aHr[4], aLr[4];
#pragma unroll
        for (int ks = 0; ks < 4; ++ks) {
            ld_a16(&aHr[ks], (const void*)(pA + ks * 32));
            ld_a16(&aLr[ks], (const void*)(pA + 262144u + ks * 32));
        }
        asm volatile("s_waitcnt vmcnt(0)" ::: "memory");
        __builtin_amdgcn_sched_barrier(0);

        f32x4 aHH[4], aHL[4], aLH[4];
#pragma unroll
        for (int jj = 0; jj < 4; ++jj) {
            aHH[jj] = (f32x4){0.f, 0.f, 0.f, 0.f};
            aHL[jj] = (f32x4){0.f, 0.f, 0.f, 0.f};
            aLH[jj] = (f32x4){0.f, 0.f, 0.f, 0.f};
        }
#pragma unroll
        for (int ks = 0; ks < 4; ++ks) {
            short8v ah, al;
            __builtin_memcpy(&ah, &aHr[ks], 16);
            __builtin_memcpy(&al, &aLr[ks], 16);
#pragma unroll
            for (int jj = 0; jj < 4; ++jj) {
                aHH[jj] = MFMA16(ah, bh[ks][jj], aHH[jj]);
                aHL[jj] = MFMA16(ah, bl[ks][jj], aHL[jj]);
                aLH[jj] = MFMA16(al, bh[ks][jj], aLH[jj]);
            }
        }

        // ---- split-K partials to LDS ----
        const int r0 = (lane >> 4) * 4;
#pragma unroll
        for (int jj = 0; jj < 4; ++jj) {
            f32x4 s = aHH[jj] + aHL[jj] + aLH[jj];
            const int col = 16 * jj + r16;
#pragma unroll
            for (int qq = 0; qq < 4; ++qq) Ps[w][r0 + qq][col] = s[qq];
        }
        __syncthreads();

        // ---- combine producer bits (wave 0) — pure function of bits-at-gen ----
        if (w == 0) {
            unsigned b = (lane < 16) ? sbits[lane] : 1u;
            unsigned long long allm = __ballot((b & 1u) != 0u);
            unsigned long long anym = __ballot((lane < 16) && ((b & 1u) != 0u));
            if (lane == 0) sres = ((allm == ~0ull) ? 2u : 0u) | ((anym != 0ull) ? 1u : 0u);
        }

        // ---- cross-wave reduce + epilogue (all state in registers) ----
        float s0 = 0.f, s1 = 0.f;
#pragma unroll
        for (int ww = 0; ww < 8; ++ww) { s0 += Ps[ww][er][ec]; s1 += Ps[ww][er][ec + 1]; }
        float n0 = softthr(hc0 + lr * (breg.x - s0), th);
        float n1 = softthr(hc1 + lr * (breg.y - s1), th);

        ushort q0 = f2bf(n0), q1 = f2bf(n1);
        st_u_sc((unsigned*)&hi_out[gi0], ((unsigned)q1 << 16) | (unsigned)q0);
        ushort z0 = f2bf(n0 - bf2f(q0)), z1 = f2bf(n1 - bf2f(q1));
        st_u_sc((unsigned*)&hi_out[262144u + gi0], ((unsigned)z1 << 16) | (unsigned)z0);

        // per-row delta partial (cadence 4 — bookkeeper reads at it&3==3 only)
        float d0 = n0 - hc0, d1 = n1 - hc1;
        hc0 = n0; hc1 = n1;
        float ssq = d0 * d0 + d1 * d1;
#pragma unroll
        for (int off = 1; off < 32; off <<= 1) ssq += __shfl_xor(ssq, off);
        if ((it & 3) == 3 && (tid & 31) == 0) st_f_sc(&rdp[bid * 16 + er], ssq);

        // ---- drain stores; read decision; arrive or stop ----
        vmdrain();
        __syncthreads();
        const unsigned res = sres;
        sticky |= (res & 1u) | sStick;
        ++gen;
        if (res & 2u) {
            // all 16 bits at gen-1 set -> unanimous stop; write final h from regs
            *(float2*)&dout[gi0] = make_float2(hc0, hc1);
            return;
        }
        if (tid == 0) st_flag(&flg[bid * 16], (gen << 2) | (sticky << 1) | stPub);
        stPub = sticky;

        // bookkeeper (wave 1, cadence 4, rotating block): off critical path.
        // racy-read tolerant (stale -> stop lags; h frozen at convergence)
        if (w == 1 && (it & 3) == 3 && bid == pod16 + ((it >> 2) & 15)) {
            float v0, v1, v2, v3;
            const float* rp = rdp + by * 256;
            ld_f_nw(&v0, rp + lane);
            ld_f_nw(&v1, rp + lane + 64);
            ld_f_nw(&v2, rp + lane + 128);
            ld_f_nw(&v3, rp + lane + 192);
            vmdrain(); __builtin_amdgcn_sched_barrier(0);
            float s = v0 + v1 + v2 + v3;          // same row (lane&15), 4 bx-groups
            s += __shfl_xor(s, 16);
            s += __shfl_xor(s, 32);               // full row sums
            float m = s;
            m = fmaxf(m, __shfl_xor(m, 1));
            m = fmaxf(m, __shfl_xor(m, 2));
            m = fmaxf(m, __shfl_xor(m, 4));
            m = fmaxf(m, __shfl_xor(m, 8));
            if (lane == 0) {
                if (m < TOL2)
                    __hip_atomic_fetch_or(podmask, 1u << by, __ATOMIC_RELAXED, __HIP_MEMORY_SCOPE_AGENT);
                unsigned pmv = ld_flag(podmask);
                if (pmv == 0xFFFFu) sStick = 1u;   // LDS; read next iter
            }
        }

        // ---- pre-issue next iteration's producer flag reads (fold poll RTT) ----
        if (lane < 2) ld_u_nw(&vpre, lane ? fprod1 : fprod0);
    }
    // loop exhausted (1000 iters): write final h from regs
    *(float2*)&dout[gi0] = make_float2(hc0, hc1);
}

extern "C" void kernel_launch(void* const* d_in, const int* in_sizes, int n_in,
                              void* d_out, int out_size, void* d_ws, size_t ws_size,
                              hipStream_t stream) {
    const float* x = (const float*)d_in[0];   // [256,512]
    const float* D = (const float*)d_in[1];   // [1024,512]
    float* out = (float*)d_out;               // [256,1024] = h
    float* ws = (float*)d_ws;

    // bf16 A-set (hiA, loA) = 0  (h0 = 0; dout is only written at exit now)
    (void)hipMemsetAsync((char*)(ws + OFF_BF), 0, 1048576, stream);
    k_init<<<dim3(1), dim3(1024), 0, stream>>>(ws);

    // G = D D^T ; bf16 split of G ; b = x D^T
    k_gemm_nt<<<dim3(32, 32), dim3(256), 0, stream>>>(ws + OFF_G, D, D, 1024, 1024, 512);
    k_conv_g<<<dim3(1024), dim3(256), 0, stream>>>(ws);
    k_gemm_nt<<<dim3(32, 8), dim3(256), 0, stream>>>(ws + OFF_B, x, D, 256, 1024, 512);

    // persistent Lanczos + Sturm + ISTA
    void* args[] = { (void*)&ws, (void*)&out };
    (void)hipLaunchCooperativeKernel((const void*)k_persist, dim3(256), dim3(512), args, 0, stream);
}

// Round 15
// 4587.161 us; speedup vs baseline: 1.0358x; 1.0358x over previous
//
#include <hip/hip_runtime.h>
#include <math.h>

#define DICT 1024
#define IN_DIM 512
#define BATCH 256
#define LMBD_F 0.1f
#define TOL2 1e-8f       // tol^2 (compare squared row norms)
#define MAX_ITERS 1000
#define LM 64            // Lanczos iterations

// ---- workspace layout (float offsets) ----
#define OFF_G      0u            // 1024*1024 f32 Gram
#define OFF_B      1048576u      // 256*1024 f32  b = x D^T
#define OFF_HA     1310720u      // 256*1024 f32  h ping (pong = d_out)
#define OFF_W      1572864u      // 1024 Lanczos w (only shared Lanczos state)
#define OFF_RDP    1573888u      // 4096: per-block row-delta partials [bid*16 + r]
#define OFF_FLG    1577984u      // 4096 uints: 256 flags, stride 16 (64B lines)
#define OFF_PM     1582080u      // podmask (uint) + pad
#define OFF_BF     1582592u      // bf16 h arrays: 4 x 262144 ushort (hiA,loA,hiB,loB)
#define OFF_GBF    2106880u      // bf16 G arrays: 2 x 1048576 ushort (Ghi,Glo)

typedef __attribute__((ext_vector_type(8))) short short8v;  // 8 bf16
typedef __attribute__((ext_vector_type(4))) float f32x4;    // MFMA C/D + asm operands
typedef __attribute__((ext_vector_type(4))) int i32x4;      // asm 16B payload

#define MFMA16(a, b, c) __builtin_amdgcn_mfma_f32_16x16x32_bf16(a, b, c, 0, 0, 0)

__device__ __forceinline__ ushort f2bf(float v) {      // f32 -> bf16 (RNE)
    union { float f; unsigned u; } x; x.f = v;
    unsigned r = x.u + 0x7fffu + ((x.u >> 16) & 1u);
    return (ushort)(r >> 16);
}
__device__ __forceinline__ float bf2f(ushort b) {
    union { unsigned u; float f; } x; x.u = ((unsigned)b) << 16;
    return x.f;
}
__device__ __forceinline__ float softthr(float aa, float th) {
    float s = fabsf(aa) - th;
    return s > 0.f ? copysignf(s, aa) : 0.f;
}

// ---- device-coherent access: sc1 = bypass L1/L2, served at IC ----
__device__ __forceinline__ void vmdrain() { asm volatile("s_waitcnt vmcnt(0)" ::: "memory"); }
__device__ __forceinline__ unsigned ld_flag(const unsigned* p) {
    unsigned v;
    asm volatile("global_load_dword %0, %1, off sc1\ns_waitcnt vmcnt(0)" : "=v"(v) : "v"(p) : "memory");
    return v;
}
// fire-and-forget flag store: ordering established by vmdrain() BEFORE it
__device__ __forceinline__ void st_flag(unsigned* p, unsigned v) {
    asm volatile("global_store_dword %0, %1, off sc1" :: "v"(p), "v"(v) : "memory");
}
__device__ __forceinline__ float ld_f_sc(const float* p) {
    float v;
    asm volatile("global_load_dword %0, %1, off sc1\ns_waitcnt vmcnt(0)" : "=v"(v) : "v"(p) : "memory");
    return v;
}
__device__ __forceinline__ void st_f_sc(float* p, float v) {
    asm volatile("global_store_dword %0, %1, off sc1" :: "v"(p), "v"(v) : "memory");
}
__device__ __forceinline__ f32x4 ld_f4_sc(const float* p) {
    f32x4 v;
    asm volatile("global_load_dwordx4 %0, %1, off sc1\ns_waitcnt vmcnt(0)" : "=v"(v) : "v"(p) : "memory");
    return v;
}
__device__ __forceinline__ void st_u_sc(unsigned* p, unsigned v) {
    asm volatile("global_store_dword %0, %1, off sc1" :: "v"(p), "v"(v) : "memory");
}
// no-wait loads: caller MUST vmdrain + sched_barrier(0) before using results (rule #18)
__device__ __forceinline__ void ld_a16(i32x4* d, const void* p) {
    asm volatile("global_load_dwordx4 %0, %1, off sc1" : "=v"(*d) : "v"(p));
}
__device__ __forceinline__ void ld_u_nw(unsigned* d, const unsigned* p) {
    asm volatile("global_load_dword %0, %1, off sc1" : "=v"(*d) : "v"(p));
}
__device__ __forceinline__ void ld_f_nw(float* d, const float* p) {
    asm volatile("global_load_dword %0, %1, off sc1" : "=v"(*d) : "v"(p));
}

// ---------------- init (runs every launch: resets ALL iteration state) ----------------
__global__ void k_init(float* ws) {
    int t = threadIdx.x;  // 1024 threads
    unsigned* flg = (unsigned*)(ws + OFF_FLG);
#pragma unroll
    for (int j = 0; j < 4; ++j) flg[t + 1024 * j] = 0u;
#pragma unroll
    for (int j = 0; j < 4; ++j) ws[OFF_RDP + t + 1024 * j] = 1e30f;
    if (t == 0) *(unsigned*)(ws + OFF_PM) = 0u;
}

// ---------------- one-time NT GEMM: C[M,N] = A[M,K] * B[N,K]^T ----------------
__global__ void k_gemm_nt(float* __restrict__ C, const float* __restrict__ A,
                          const float* __restrict__ B, int M, int N, int K) {
    __shared__ float As[32][33];
    __shared__ float Bs[32][33];
    const int tid = threadIdx.x;
    const int m0 = blockIdx.y * 32, n0 = blockIdx.x * 32;
    const int lrw = tid >> 3;
    const int lc4 = (tid & 7) * 4;
    const int ty = tid >> 4, tx = tid & 15;
    float acc00 = 0, acc01 = 0, acc10 = 0, acc11 = 0;
    for (int k0 = 0; k0 < K; k0 += 32) {
        float4 av = *(const float4*)&A[(m0 + lrw) * K + k0 + lc4];
        float4 bv = *(const float4*)&B[(n0 + lrw) * K + k0 + lc4];
        __syncthreads();
        As[lrw][lc4 + 0] = av.x; As[lrw][lc4 + 1] = av.y;
        As[lrw][lc4 + 2] = av.z; As[lrw][lc4 + 3] = av.w;
        Bs[lrw][lc4 + 0] = bv.x; Bs[lrw][lc4 + 1] = bv.y;
        Bs[lrw][lc4 + 2] = bv.z; Bs[lrw][lc4 + 3] = bv.w;
        __syncthreads();
#pragma unroll
        for (int k = 0; k < 32; ++k) {
            float a0 = As[ty * 2][k], a1 = As[ty * 2 + 1][k];
            float b0 = Bs[tx * 2][k], b1 = Bs[tx * 2 + 1][k];
            acc00 += a0 * b0; acc01 += a0 * b1;
            acc10 += a1 * b0; acc11 += a1 * b1;
        }
    }
    C[(m0 + ty * 2) * N + n0 + tx * 2] = acc00;
    C[(m0 + ty * 2) * N + n0 + tx * 2 + 1] = acc01;
    C[(m0 + ty * 2 + 1) * N + n0 + tx * 2] = acc10;
    C[(m0 + ty * 2 + 1) * N + n0 + tx * 2 + 1] = acc11;
}

// ---------------- convert G f32 -> (Ghi, Glo) bf16, once ----------------
__global__ void k_conv_g(float* ws) {
    const int i = (blockIdx.x * 256 + threadIdx.x) * 4;
    const float* G = ws + OFF_G;
    ushort* Ghi = (ushort*)(ws + OFF_GBF);
    ushort* Glo = Ghi + 1048576u;
    float4 g = *(const float4*)&G[i];
    ushort h0 = f2bf(g.x), h1 = f2bf(g.y), h2 = f2bf(g.z), h3 = f2bf(g.w);
    *(ushort4*)&Ghi[i] = make_ushort4(h0, h1, h2, h3);
    ushort l0 = f2bf(g.x - bf2f(h0)), l1 = f2bf(g.y - bf2f(h1));
    ushort l2 = f2bf(g.z - bf2f(h2)), l3 = f2bf(g.w - bf2f(h3));
    *(ushort4*)&Glo[i] = make_ushort4(l0, l1, l2, l3);
}

// ---------------- persistent kernel ----------------
// 256 blocks x 512 threads. Lanczos: global parallel flag barrier + redundant
// per-block alpha/beta. Sturm: per-block. ISTA: per-wave producer dataflow —
// wave w waits only on its 2 K-range producers (px=2w,2w+1). Flag word =
// (gen<<2)|(bit_cur<<1)|bit_prev; drift<=1 makes bit-at-gen well-defined ->
// unanimous stop. Bookkeeper cadence 4, off-path.
__launch_bounds__(512, 2)
__global__ void k_persist(float* __restrict__ ws, float* __restrict__ dout) {
    const int tid = threadIdx.x;
    const int bid = blockIdx.x;
    const int w = tid >> 6, lane = tid & 63;
    unsigned* flg = (unsigned*)(ws + OFF_FLG);
    unsigned* podmask = (unsigned*)(ws + OFF_PM);
    float* Wg = ws + OFF_W;
    float* rdp = ws + OFF_RDP;
    const float* G = ws + OFF_G;

    __shared__ float Ps[8][16][64];   // split-K partials, 32 KB
    __shared__ float Vl[1024], VPl[1024], Wl[1024];
    __shared__ float aArr[LM], bArr[LM];
    __shared__ float sred[8];
    __shared__ float scal2[2];
    __shared__ unsigned sres;
    __shared__ unsigned sbits[16];
    __shared__ unsigned sStick;

    unsigned gen = 0;

    const int bx = bid & 15;            // col tile (64 cols)
    const int by = bid >> 4;            // row tile (16 rows) == pod id
    const int R0 = by * 16, C0 = bx * 64;
    const int pod16 = by * 16;          // first bid of pod

    // ================= Lanczos: redundant alpha/beta, shared W only =================
    if (tid < 512) {
        Vl[tid] = 0.03125f; Vl[tid + 512] = 0.03125f;
        VPl[tid] = 0.f;     VPl[tid + 512] = 0.f;
    }
    __syncthreads();
    float bprev = 0.f;
#pragma unroll 1
    for (int j = 0; j < LM; ++j) {
        // matvec: this block computes W rows 4*bid .. 4*bid+3 from local Vl
        {
            const int row = tid >> 7, sub = tid & 127;
            const float* gr = G + (bid * 4 + row) * DICT;
            float s = 0.f;
#pragma unroll
            for (int jj = 0; jj < 8; ++jj) s += gr[sub + 128 * jj] * Vl[sub + 128 * jj];
#pragma unroll
            for (int off = 32; off; off >>= 1) s += __shfl_down(s, off);
            if (lane == 0) sred[w] = s;
            __syncthreads();
            if (tid < 4) st_f_sc(Wg + bid * 4 + tid, sred[2 * tid] + sred[2 * tid + 1]);
        }
        // global parallel flag barrier
        ++gen;
        vmdrain(); __syncthreads();
        if (tid == 0) st_flag(&flg[bid * 16], gen << 2);
        if (w == 0) {
            for (;;) {
                unsigned v0, v1, v2, v3;
                ld_u_nw(&v0, &flg[lane * 16]);
                ld_u_nw(&v1, &flg[(lane + 64) * 16]);
                ld_u_nw(&v2, &flg[(lane + 128) * 16]);
                ld_u_nw(&v3, &flg[(lane + 192) * 16]);
                vmdrain(); __builtin_amdgcn_sched_barrier(0);
                bool ok = ((v0 >> 2) >= gen) && ((v1 >> 2) >= gen) &&
                          ((v2 >> 2) >= gen) && ((v3 >> 2) >= gen);
                if (__ballot(ok) == ~0ull) break;
                __builtin_amdgcn_s_sleep(1);
            }
        }
        __syncthreads();
        // redundant: read full W, compute alpha/beta, update Vl/VPl locally
        if (tid < 256) { f32x4 w4 = ld_f4_sc(Wg + tid * 4); *(f32x4*)&Wl[tid * 4] = w4; }
        __syncthreads();
        float p = Vl[tid] * Wl[tid] + Vl[tid + 512] * Wl[tid + 512];
#pragma unroll
        for (int off = 32; off; off >>= 1) p += __shfl_down(p, off);
        if (lane == 0) sred[w] = p;
        __syncthreads();
        float alpha = sred[0] + sred[1] + sred[2] + sred[3] + sred[4] + sred[5] + sred[6] + sred[7];
        float u0 = Wl[tid] - alpha * Vl[tid] - bprev * VPl[tid];
        float u1 = Wl[tid + 512] - alpha * Vl[tid + 512] - bprev * VPl[tid + 512];
        float qq = u0 * u0 + u1 * u1;
        __syncthreads();   // sred reuse
#pragma unroll
        for (int off = 32; off; off >>= 1) qq += __shfl_down(qq, off);
        if (lane == 0) sred[w] = qq;
        __syncthreads();
        float beta = sqrtf(sred[0] + sred[1] + sred[2] + sred[3] + sred[4] + sred[5] + sred[6] + sred[7]);
        float bsafe = (beta > 1e-20f) ? beta : 0.f;
        float inv = (beta > 1e-20f) ? 1.f / beta : 0.f;
        VPl[tid] = Vl[tid]; VPl[tid + 512] = Vl[tid + 512];
        Vl[tid] = u0 * inv; Vl[tid + 512] = u1 * inv;
        if (tid == 0) { aArr[j] = alpha; bArr[j] = bsafe; }
        bprev = bsafe;
        __syncthreads();
    }

    // ================= Sturm bisection (per block, wave 0) -> lr, thresh =================
    if (tid < 64) {
        double lo = 0.0, hi = 0.0;
        for (int i = 0; i < LM; ++i) {
            double bi  = fabs((double)bArr[i]);
            double bim = i ? fabs((double)bArr[i - 1]) : 0.0;
            double r = (double)aArr[i] + bi + bim;
            if (r > hi) hi = r;
        }
        for (int rnd = 0; rnd < 4; ++rnd) {
            double midt = lo + (hi - lo) * ((double)(tid + 1) / 65.0);
            int cntn = 0; double d = 1.0;
            for (int i = 0; i < LM; ++i) {
                double bm = i ? (double)bArr[i - 1] : 0.0;
                d = ((double)aArr[i] - midt) - (bm * bm) / d;
                if (d == 0.0) d = -1e-300;
                if (d < 0.0) cntn++;
            }
            unsigned long long m = __ballot(cntn >= LM);
            int first = (m == 0ull) ? 64 : (__ffsll((unsigned long long)m) - 1);
            double nlo = lo + (hi - lo) * ((double)first / 65.0);
            double nhi = (first == 64) ? hi : lo + (hi - lo) * ((double)(first + 1) / 65.0);
            lo = nlo; hi = nhi;
        }
        if (tid == 0) {
            float lam = (float)(0.5 * (lo + hi));
            float lrv = 0.99f / lam;
            scal2[0] = lrv;
            scal2[1] = lrv * LMBD_F;
        }
    }
    if (tid == 0) sStick = 0u;
    __syncthreads();
    const float lr = scal2[0], th = scal2[1];

    // ================= ISTA: per-wave producer dataflow =================
    ushort* bfb = (ushort*)(ws + OFF_BF);
    const ushort* Ghi = (const ushort*)(ws + OFF_GBF);
    const float* bv_ = ws + OFF_B;
    float* hA = ws + OFF_HA;
    const int r16 = lane & 15, kk8 = (lane >> 4) * 8;
    const int er = tid >> 5;          // 0..15
    const int ec = (tid & 31) * 2;    // 0..62

    // hoist G fragments into registers (reused all iters)
    const ushort* pB = Ghi + (C0 + r16) * DICT + w * 128 + kk8;
    short8v bh[4][4], bl[4][4];
#pragma unroll
    for (int ks = 0; ks < 4; ++ks)
#pragma unroll
        for (int jj = 0; jj < 4; ++jj) {
            bh[ks][jj] = *(const short8v*)(pB + jj * 16 * DICT + ks * 32);
            bl[ks][jj] = *(const short8v*)(pB + 1048576u + jj * 16 * DICT + ks * 32);
        }

    unsigned sticky = 0, stPub = 0;
    // this wave's two producer flags (own K-range [w*128, w*128+128))
    const unsigned* fprod0 = &flg[(pod16 + 2 * w) * 16];
    const unsigned* fprod1 = &flg[(pod16 + 2 * w + 1) * 16];

#pragma unroll 1
    for (int it = 0; it < MAX_ITERS; ++it) {
        const float* h_in = (it & 1) ? hA : dout;      // f32 ping (block-private tiles)
        float* h_out      = (it & 1) ? dout : hA;
        const ushort* hi_in = bfb + ((it & 1) ? 524288u : 0u);
        ushort* hi_out = bfb + ((it & 1) ? 0u : 524288u);

        // ---- per-wave: wait for this wave's 2 producers at gen; collect bit-at-gen ----
        if (lane < 2) {
            const unsigned* fp = lane ? fprod1 : fprod0;
            unsigned v; int spins = 0;
            for (;;) {
                v = ld_flag(fp);
                if ((v >> 2) >= gen) break;
                __builtin_amdgcn_s_sleep(1);
                if (++spins > (1 << 25)) break;    // diagnostic bail (unreachable if logic sound)
            }
            // drift <= 1: flag gen == gen -> cur bit; gen+1 -> prev bit
            sbits[2 * w + lane] = ((v >> 2) == gen) ? ((v >> 1) & 1u) : (v & 1u);
        }
        // wave reconverged: producers' h visible; issue A-loads for our K-chunk
        const ushort* pA = hi_in + (R0 + r16) * DICT + w * 128 + kk8;
        i32x4 aHr[4], aLr[4];
#pragma unroll
        for (int ks = 0; ks < 4; ++ks) {
            ld_a16(&aHr[ks], (const void*)(pA + ks * 32));
            ld_a16(&aLr[ks], (const void*)(pA + 262144u + ks * 32));
        }
        asm volatile("s_waitcnt vmcnt(0)" ::: "memory");
        __builtin_amdgcn_sched_barrier(0);

        f32x4 aHH[4], aHL[4], aLH[4];
#pragma unroll
        for (int jj = 0; jj < 4; ++jj) {
            aHH[jj] = (f32x4){0.f, 0.f, 0.f, 0.f};
            aHL[jj] = (f32x4){0.f, 0.f, 0.f, 0.f};
            aLH[jj] = (f32x4){0.f, 0.f, 0.f, 0.f};
        }
#pragma unroll
        for (int ks = 0; ks < 4; ++ks) {
            short8v ah, al;
            __builtin_memcpy(&ah, &aHr[ks], 16);
            __builtin_memcpy(&al, &aLr[ks], 16);
#pragma unroll
            for (int jj = 0; jj < 4; ++jj) {
                aHH[jj] = MFMA16(ah, bh[ks][jj], aHH[jj]);
                aHL[jj] = MFMA16(ah, bl[ks][jj], aHL[jj]);
                aLH[jj] = MFMA16(al, bh[ks][jj], aLH[jj]);
            }
        }

        // ---- split-K partials to LDS ----
        const int r0 = (lane >> 4) * 4;
#pragma unroll
        for (int jj = 0; jj < 4; ++jj) {
            f32x4 s = aHH[jj] + aHL[jj] + aLH[jj];
            const int col = 16 * jj + r16;
#pragma unroll
            for (int qq = 0; qq < 4; ++qq) Ps[w][r0 + qq][col] = s[qq];
        }
        __syncthreads();

        // ---- combine producer bits (wave 0) — pure function of bits-at-gen ----
        if (w == 0) {
            unsigned b = (lane < 16) ? sbits[lane] : 1u;
            unsigned long long allm = __ballot((b & 1u) != 0u);
            unsigned long long anym = __ballot((lane < 16) && ((b & 1u) != 0u));
            if (lane == 0) sres = ((allm == ~0ull) ? 2u : 0u) | ((anym != 0ull) ? 1u : 0u);
        }

        // ---- cross-wave reduce + epilogue ----
        float s0 = 0.f, s1 = 0.f;
#pragma unroll
        for (int ww = 0; ww < 8; ++ww) { s0 += Ps[ww][er][ec]; s1 += Ps[ww][er][ec + 1]; }
        const int gi = (R0 + er) * DICT + C0 + ec;
        float2 bb = *(const float2*)&bv_[gi];
        float2 hh = *(const float2*)&h_in[gi];
        float n0 = softthr(hh.x + lr * (bb.x - s0), th);
        float n1 = softthr(hh.y + lr * (bb.y - s1), th);
        *(float2*)&h_out[gi] = make_float2(n0, n1);

        ushort q0 = f2bf(n0), q1 = f2bf(n1);
        st_u_sc((unsigned*)&hi_out[gi], ((unsigned)q1 << 16) | (unsigned)q0);
        ushort z0 = f2bf(n0 - bf2f(q0)), z1 = f2bf(n1 - bf2f(q1));
        st_u_sc((unsigned*)&hi_out[262144u + gi], ((unsigned)z1 << 16) | (unsigned)z0);

        // per-row delta partial -> private slot (no atomics)
        float d0 = n0 - hh.x, d1 = n1 - hh.y;
        float ssq = d0 * d0 + d1 * d1;
#pragma unroll
        for (int off = 1; off < 32; off <<= 1) ssq += __shfl_xor(ssq, off);
        if ((tid & 31) == 0) st_f_sc(&rdp[bid * 16 + er], ssq);

        // ---- drain stores; read decision; arrive or stop ----
        vmdrain();
        __syncthreads();
        const unsigned res = sres;
        sticky |= (res & 1u) | sStick;
        ++gen;
        if (res & 2u) {
            // all 16 bits at gen-1 set -> unanimous stop after this iter.
            // latest h = h_out(it): already in dout if it odd, else copy hA tile.
            if ((it & 1) == 0) {
                const int g2 = (R0 + er) * DICT + C0 + ec;
                *(float2*)&dout[g2] = *(const float2*)&hA[g2];
            }
            return;
        }
        if (tid == 0) st_flag(&flg[bid * 16], (gen << 2) | (sticky << 1) | stPub);
        stPub = sticky;

        // bookkeeper (wave 1, cadence 4, rotating block): off critical path.
        // racy-read tolerant (stale -> stop lags; h frozen at convergence)
        if (w == 1 && (it & 3) == 3 && bid == pod16 + ((it >> 2) & 15)) {
            float v0, v1, v2, v3;
            const float* rp = rdp + by * 256;
            ld_f_nw(&v0, rp + lane);
            ld_f_nw(&v1, rp + lane + 64);
            ld_f_nw(&v2, rp + lane + 128);
            ld_f_nw(&v3, rp + lane + 192);
            vmdrain(); __builtin_amdgcn_sched_barrier(0);
            float s = v0 + v1 + v2 + v3;          // same row (lane&15), 4 bx-groups
            s += __shfl_xor(s, 16);
            s += __shfl_xor(s, 32);               // full row sums
            float m = s;
            m = fmaxf(m, __shfl_xor(m, 1));
            m = fmaxf(m, __shfl_xor(m, 2));
            m = fmaxf(m, __shfl_xor(m, 4));
            m = fmaxf(m, __shfl_xor(m, 8));
            if (lane == 0) {
                if (m < TOL2)
                    __hip_atomic_fetch_or(podmask, 1u << by, __ATOMIC_RELAXED, __HIP_MEMORY_SCOPE_AGENT);
                unsigned pmv = ld_flag(podmask);
                if (pmv == 0xFFFFu) sStick = 1u;   // LDS; read next iter after barrier
            }
        }
    }
}

extern "C" void kernel_launch(void* const* d_in, const int* in_sizes, int n_in,
                              void* d_out, int out_size, void* d_ws, size_t ws_size,
                              hipStream_t stream) {
    const float* x = (const float*)d_in[0];   // [256,512]
    const float* D = (const float*)d_in[1];   // [1024,512]
    float* out = (float*)d_out;               // [256,1024] = h
    float* ws = (float*)d_ws;

    // h0 = 0 (f32 ping in d_out) and bf16 A-set (hiA, loA) = 0
    (void)hipMemsetAsync(d_out, 0, (size_t)BATCH * DICT * sizeof(float), stream);
    (void)hipMemsetAsync((char*)(ws + OFF_BF), 0, 1048576, stream);
    k_init<<<dim3(1), dim3(1024), 0, stream>>>(ws);

    // G = D D^T ; bf16 split of G ; b = x D^T
    k_gemm_nt<<<dim3(32, 32), dim3(256), 0, stream>>>(ws + OFF_G, D, D, 1024, 1024, 512);
    k_conv_g<<<dim3(1024), dim3(256), 0, stream>>>(ws);
    k_gemm_nt<<<dim3(32, 8), dim3(256), 0, stream>>>(ws + OFF_B, x, D, 256, 1024, 512);

    // persistent Lanczos + Sturm + ISTA
    void* args[] = { (void*)&ws, (void*)&out };
    (void)hipLaunchCooperativeKernel((const void*)k_persist, dim3(256), dim3(512), args, 0, stream);
}